// Round 2
// baseline (5008.187 us; speedup 1.0000x reference)
//
#include <hip/hip_runtime.h>

#define B 8
#define CIN 64
#define NPT 50000
#define L 256
#define TC 128

// ---------------- KNN gather + max-pool: pooled[b,c,l] = max_k f[b,c,knn[b,l,k]] ----------------
__global__ void k_gather(const float* __restrict__ f, const int* __restrict__ knn,
                         float* __restrict__ pooled) {
    int id = blockIdx.x * 256 + threadIdx.x;       // (b, c, l), l fastest
    int l = id & 255;
    int c = (id >> 8) & 63;
    int b = id >> 14;
    const int* kn = knn + (b * L + l) * 32;
    const float* fr = f + (b * CIN + c) * NPT;
    float m = -1e30f;
    #pragma unroll 8
    for (int k = 0; k < 32; k++) m = fmaxf(m, fr[kn[k]]);
    pooled[(b * CIN + c) * L + l] = m;
}

// ---------------- generic 1x1 conv over tokens: out[b,o,l] = act(sum_c w[o,c] in[b,c,l]) ----------------
template <int O, int C, bool RELU>
__global__ void k_conv(const float* __restrict__ in, const float* __restrict__ w,
                       const float* __restrict__ res, float* __restrict__ out,
                       float* __restrict__ out2) {
    int id = blockIdx.x * 256 + threadIdx.x;       // (b, o, l), l fastest
    int l = id & 255;
    int o = (id >> 8) % O;
    int b = id / (O * 256);
    const float* ir = in + b * C * L + l;
    const float* wr = w + o * C;
    float acc = 0.f;
    #pragma unroll 8
    for (int c = 0; c < C; c++) acc += wr[c] * ir[c * L];
    if (RELU) acc = fmaxf(acc, 0.f);
    if (res) acc += res[id];
    out[id] = acc;
    if (out2) out2[id] = acc;
}

// ---------------- token attention: attn[b,h,n,m] = softmax_n( (k[:,n]·q[:,m]) / 16 ) ----------------
__global__ void k_attn(const float* __restrict__ kmat, const float* __restrict__ qmat,
                       float* __restrict__ attn) {
    int blk = blockIdx.x;                           // (b, h, m)
    int m = blk & 255;
    int h = (blk >> 8) & 1;
    int b = blk >> 9;
    int n = threadIdx.x;
    const float* kr = kmat + (b * 64 + h * 32) * L + n;
    const float* qr = qmat + (b * 64 + h * 32) * L + m;
    float s = 0.f;
    #pragma unroll
    for (int d = 0; d < 32; d++) s += kr[d * L] * qr[d * L];
    s *= (1.f / 16.f);
    __shared__ float sm[256];
    sm[n] = s;
    __syncthreads();
    for (int st = 128; st > 0; st >>= 1) { if (n < st) sm[n] = fmaxf(sm[n], sm[n + st]); __syncthreads(); }
    float mx = sm[0];
    __syncthreads();
    float p = __expf(s - mx);
    sm[n] = p;
    __syncthreads();
    for (int st = 128; st > 0; st >>= 1) { if (n < st) sm[n] += sm[n + st]; __syncthreads(); }
    float Z = sm[0];
    attn[((b * 2 + h) * L + n) * L + m] = p / Z;
}

// ---------------- kqv + residual: t1[b,ch,m] = tokens[b,ch,m] + sum_n v[b,ch,n] attn[b,h,n,m] ----------------
__global__ void k_kqv(const float* __restrict__ vmat, const float* __restrict__ attn,
                      const float* __restrict__ tokens, float* __restrict__ t1) {
    int id = blockIdx.x * 256 + threadIdx.x;       // (b, ch, m)
    int m = id & 255;
    int ch = (id >> 8) & 127;
    int b = id >> 15;
    int h = ch >> 6;
    const float* vr = vmat + (b * TC + ch) * L;
    const float* ar = attn + ((b * 2 + h) * L) * L + m;
    float acc = 0.f;
    #pragma unroll 8
    for (int n = 0; n < L; n++) acc += vr[n] * ar[n * L];
    t1[id] = tokens[id] + acc;
}

// ---------------- pkq[b,h,l,e] = (1/8) sum_d pk[b,h*64+d,l] * w_pq[h*64+d,e] ----------------
__global__ void k_pkq(const float* __restrict__ pk, const float* __restrict__ wpq,
                      float* __restrict__ pkqo) {
    int id = blockIdx.x * 256 + threadIdx.x;       // (b, h, l, e), e fastest
    int e = id & 127;
    int l = (id >> 7) & 255;
    int h = (id >> 15) & 1;
    int b = id >> 16;
    const float* pkr = pk + (b * TC + h * 64) * L + l;
    const float* wr = wpq + (h * 64) * TC + e;
    float acc = 0.f;
    #pragma unroll 8
    for (int d = 0; d < 64; d++) acc += pkr[d * L] * wr[d * TC];
    pkqo[id] = acc * 0.125f;
}

// ---------------- fused projector: x = w_fb@f; s = pkq@x; softmax over l; out = x + pv@coef ----------------
// block: 64 points of one batch, 256 threads (4 waves). wave w = tid>>6, lane p = tid&63.
__global__ __launch_bounds__(256) void k_proj(const float* __restrict__ f,
                                              const float* __restrict__ wfb,
                                              const float* __restrict__ pkqt,   // (B,2,256,128), pre-scaled
                                              const float* __restrict__ pv,    // (B,128,256)
                                              float* __restrict__ out, int N) {
    const int b = blockIdx.y;
    const int n0 = blockIdx.x * 64;
    const int tid = threadIdx.x;
    const int w = tid >> 6, p = tid & 63;

    __shared__ float xt[128][64];   // x tile, e-major
    __shared__ float u[64][64];     // f tile, then P tile
    __shared__ float red[4][64];    // cross-wave reduction

    // phase 0: stage f tile (coalesced)
    #pragma unroll
    for (int i = 0; i < 16; i++) {
        int lin = tid + i * 256;
        int c = lin >> 6, pp = lin & 63;
        int n = n0 + pp;
        u[c][pp] = (n < N) ? f[(b * CIN + c) * N + n] : 0.f;
    }
    __syncthreads();

    // phase 1: x[e,p] = sum_c w_fb[e,c] f[c,p];  thread: e = w*32+j
    {
        float acc[32];
        #pragma unroll
        for (int j = 0; j < 32; j++) acc[j] = 0.f;
        for (int c0 = 0; c0 < 64; c0 += 4) {
            float fc0 = u[c0][p], fc1 = u[c0 + 1][p], fc2 = u[c0 + 2][p], fc3 = u[c0 + 3][p];
            #pragma unroll
            for (int j = 0; j < 32; j++) {
                const float4 w4 = *reinterpret_cast<const float4*>(&wfb[(w * 32 + j) * 64 + c0]);
                acc[j] += w4.x * fc0 + w4.y * fc1 + w4.z * fc2 + w4.w * fc3;
            }
        }
        __syncthreads();            // everyone done reading f tile
        #pragma unroll
        for (int j = 0; j < 32; j++) xt[w * 32 + j][p] = acc[j];
    }
    __syncthreads();

    const float* pkqb = pkqt + (b * 2) * 256 * 128;
    const float* pvb = pv + b * 128 * 256;

    for (int h = 0; h < 2; h++) {
        const float* pkqh = pkqb + h * 256 * 128;
        const float* pvh = pvb + h * 64 * 256;
        float m_run = -1e30f, z_run = 0.f;
        float o[16];
        #pragma unroll
        for (int j = 0; j < 16; j++) o[j] = 0.f;

        for (int ch = 0; ch < 4; ch++) {
            // scores: thread's l = ch*64 + w*16 + j
            float s[16];
            #pragma unroll
            for (int j = 0; j < 16; j++) s[j] = 0.f;
            const float* pkqc = pkqh + (ch * 64 + w * 16) * 128;
            for (int e0 = 0; e0 < 128; e0 += 4) {
                float x0 = xt[e0][p], x1 = xt[e0 + 1][p], x2 = xt[e0 + 2][p], x3 = xt[e0 + 3][p];
                #pragma unroll
                for (int j = 0; j < 16; j++) {
                    const float4 k4 = *reinterpret_cast<const float4*>(&pkqc[j * 128 + e0]);
                    s[j] += k4.x * x0 + k4.y * x1 + k4.z * x2 + k4.w * x3;
                }
            }
            // online softmax bookkeeping
            float lmax = s[0];
            #pragma unroll
            for (int j = 1; j < 16; j++) lmax = fmaxf(lmax, s[j]);
            red[w][p] = lmax;
            __syncthreads();
            float cmax = fmaxf(fmaxf(red[0][p], red[1][p]), fmaxf(red[2][p], red[3][p]));
            float m_new = fmaxf(m_run, cmax);
            float lsum = 0.f;
            #pragma unroll
            for (int j = 0; j < 16; j++) { s[j] = __expf(s[j] - m_new); lsum += s[j]; }
            __syncthreads();        // red reads done, safe to overwrite
            red[w][p] = lsum;
            #pragma unroll
            for (int j = 0; j < 16; j++) u[w * 16 + j][p] = s[j];   // P tile
            __syncthreads();
            float csum = red[0][p] + red[1][p] + red[2][p] + red[3][p];
            float scale = __expf(m_run - m_new);   // 0 on first chunk (m_run=-1e30)
            z_run = z_run * scale + csum;
            m_run = m_new;
            #pragma unroll
            for (int j = 0; j < 16; j++) o[j] *= scale;
            // o[d,p] += sum_l pv[d, ch*64+l] * P[l,p];  thread's d = w*16+j
            const float* pvc = pvh + (w * 16) * 256 + ch * 64;
            for (int l0 = 0; l0 < 64; l0 += 4) {
                float q0 = u[l0][p], q1 = u[l0 + 1][p], q2 = u[l0 + 2][p], q3 = u[l0 + 3][p];
                #pragma unroll
                for (int j = 0; j < 16; j++) {
                    const float4 v4 = *reinterpret_cast<const float4*>(&pvc[j * 256 + l0]);
                    o[j] += v4.x * q0 + v4.y * q1 + v4.z * q2 + v4.w * q3;
                }
            }
            __syncthreads();        // P tile reads done before next chunk overwrites
        }
        // epilogue: out = x + o/Z  (coalesced stores, lanes over p)
        float inv = 1.f / z_run;
        int n = n0 + p;
        if (n < N) {
            #pragma unroll
            for (int j = 0; j < 16; j++) {
                int d = h * 64 + w * 16 + j;
                out[(b * 128 + d) * N + n] = xt[d][p] + o[j] * inv;
            }
        }
    }
}

extern "C" void kernel_launch(void* const* d_in, const int* in_sizes, int n_in,
                              void* d_out, int out_size, void* d_ws, size_t ws_size,
                              hipStream_t stream) {
    const float* f        = (const float*)d_in[0];
    const float* in_tok   = (const float*)d_in[1];
    const int*   knn      = (const int*)d_in[2];
    const float* w_dyn1   = (const float*)d_in[3];
    const float* w_dyn2   = (const float*)d_in[4];
    const float* w_fb     = (const float*)d_in[5];
    const float* w_k      = (const float*)d_in[6];
    const float* w_q      = (const float*)d_in[7];
    const float* w_v      = (const float*)d_in[8];
    const float* w_ff1    = (const float*)d_in[9];
    const float* w_ff2    = (const float*)d_in[10];
    const float* w_pv     = (const float*)d_in[11];
    const float* w_pk     = (const float*)d_in[12];
    const float* w_pq     = (const float*)d_in[13];

    float* out   = (float*)d_out;
    float* t_out = out + (size_t)B * 128 * NPT;    // second output: t (8,128,256)

    float* ws     = (float*)d_ws;
    float* pooled = ws;                  // 131072
    float* tok1   = pooled + 131072;     // 262144
    float* tokens = tok1 + 262144;       // 262144
    float* kmat   = tokens + 262144;     // 131072
    float* qmat   = kmat + 131072;       // 131072
    float* vmat   = qmat + 131072;       // 262144
    float* attn   = vmat + 262144;       // 1048576
    float* t1     = attn + 1048576;      // 262144
    float* ff1    = t1 + 262144;         // 524288
    float* tfin   = ff1 + 524288;        // 262144
    float* pvb    = tfin + 262144;       // 262144
    float* pkb    = pvb + 262144;        // 262144
    float* pkqb   = pkb + 262144;        // 524288

    k_gather<<<512, 256, 0, stream>>>(f, knn, pooled);
    k_conv<128, 64, true ><<<B * 128, 256, 0, stream>>>(pooled, w_dyn1, nullptr, tok1, nullptr);
    k_conv<128, 128, false><<<B * 128, 256, 0, stream>>>(tok1, w_dyn2, in_tok, tokens, nullptr);
    k_conv<64, 128, false><<<B * 64, 256, 0, stream>>>(tokens, w_k, nullptr, kmat, nullptr);
    k_conv<64, 128, false><<<B * 64, 256, 0, stream>>>(tokens, w_q, nullptr, qmat, nullptr);
    k_conv<128, 128, false><<<B * 128, 256, 0, stream>>>(tokens, w_v, nullptr, vmat, nullptr);
    k_attn<<<B * 2 * 256, 256, 0, stream>>>(kmat, qmat, attn);
    k_kqv<<<B * 128, 256, 0, stream>>>(vmat, attn, tokens, t1);
    k_conv<256, 128, true ><<<B * 256, 256, 0, stream>>>(t1, w_ff1, nullptr, ff1, nullptr);
    k_conv<128, 256, false><<<B * 128, 256, 0, stream>>>(ff1, w_ff2, t1, tfin, t_out);
    k_conv<128, 128, false><<<B * 128, 256, 0, stream>>>(tfin, w_pv, nullptr, pvb, nullptr);
    k_conv<128, 128, false><<<B * 128, 256, 0, stream>>>(tfin, w_pk, nullptr, pkb, nullptr);
    k_pkq<<<2048, 256, 0, stream>>>(pkb, w_pq, pkqb);

    dim3 g((NPT + 63) / 64, B);
    k_proj<<<g, 256, 0, stream>>>(f, w_fb, pkqb, pvb, out, NPT);
}

// Round 6
// 1032.941 us; speedup vs baseline: 4.8485x; 4.8485x over previous
//
#include <hip/hip_runtime.h>

#define B 8
#define CIN 64
#define NPT 50000
#define L 256
#define TC 128

typedef unsigned short ushort_t;
typedef __bf16 bf16x8 __attribute__((ext_vector_type(8)));
typedef float f32x4 __attribute__((ext_vector_type(4)));

__device__ __forceinline__ ushort_t f2b(float v) {
    union { float f; unsigned int u; } x; x.f = v;
    unsigned int r = x.u + 0x7FFFu + ((x.u >> 16) & 1u);
    return (ushort_t)(r >> 16);
}

// ---------------- KNN gather + max-pool ----------------
__global__ void k_gather(const float* __restrict__ f, const int* __restrict__ knn,
                         float* __restrict__ pooled) {
    int id = blockIdx.x * 256 + threadIdx.x;
    int l = id & 255;
    int c = (id >> 8) & 63;
    int b = id >> 14;
    const int* kn = knn + (b * L + l) * 32;
    const float* fr = f + (b * CIN + c) * NPT;
    float m = -1e30f;
    #pragma unroll 8
    for (int k = 0; k < 32; k++) m = fmaxf(m, fr[kn[k]]);
    pooled[(b * CIN + c) * L + l] = m;
}

// ---------------- generic 1x1 conv over tokens ----------------
template <int O, int C, bool RELU>
__global__ void k_conv(const float* __restrict__ in, const float* __restrict__ w,
                       const float* __restrict__ res, float* __restrict__ out,
                       float* __restrict__ out2, ushort_t* __restrict__ outb) {
    int id = blockIdx.x * 256 + threadIdx.x;
    int l = id & 255;
    int o = (id >> 8) % O;
    int b = id / (O * 256);
    const float* ir = in + b * C * L + l;
    const float* wr = w + o * C;
    float acc = 0.f;
    #pragma unroll 8
    for (int c = 0; c < C; c++) acc += wr[c] * ir[c * L];
    if (RELU) acc = fmaxf(acc, 0.f);
    if (res) acc += res[id];
    if (out)  out[id] = acc;
    if (out2) out2[id] = acc;
    if (outb) outb[id] = f2b(acc);
}

// ---------------- token attention ----------------
__global__ void k_attn(const float* __restrict__ kmat, const float* __restrict__ qmat,
                       float* __restrict__ attn) {
    int blk = blockIdx.x;
    int m = blk & 255;
    int h = (blk >> 8) & 1;
    int b = blk >> 9;
    int n = threadIdx.x;
    const float* kr = kmat + (b * 64 + h * 32) * L + n;
    const float* qr = qmat + (b * 64 + h * 32) * L + m;
    float s = 0.f;
    #pragma unroll
    for (int d = 0; d < 32; d++) s += kr[d * L] * qr[d * L];
    s *= (1.f / 16.f);
    __shared__ float sm[256];
    sm[n] = s;
    __syncthreads();
    for (int st = 128; st > 0; st >>= 1) { if (n < st) sm[n] = fmaxf(sm[n], sm[n + st]); __syncthreads(); }
    float mx = sm[0];
    __syncthreads();
    float p = __expf(s - mx);
    sm[n] = p;
    __syncthreads();
    for (int st = 128; st > 0; st >>= 1) { if (n < st) sm[n] += sm[n + st]; __syncthreads(); }
    float Z = sm[0];
    attn[((b * 2 + h) * L + n) * L + m] = p / Z;
}

// ---------------- kqv + residual ----------------
__global__ void k_kqv(const float* __restrict__ vmat, const float* __restrict__ attn,
                      const float* __restrict__ tokens, float* __restrict__ t1) {
    int id = blockIdx.x * 256 + threadIdx.x;
    int m = id & 255;
    int ch = (id >> 8) & 127;
    int b = id >> 15;
    int h = ch >> 6;
    const float* vr = vmat + (b * TC + ch) * L;
    const float* ar = attn + ((b * 2 + h) * L) * L + m;
    float acc = 0.f;
    #pragma unroll 8
    for (int n = 0; n < L; n++) acc += vr[n] * ar[n * L];
    t1[id] = tokens[id] + acc;
}

// ---------------- pkq (bf16 out, pre-scaled by 1/8) ----------------
__global__ void k_pkq(const float* __restrict__ pk, const float* __restrict__ wpq,
                      ushort_t* __restrict__ pkqo) {
    int id = blockIdx.x * 256 + threadIdx.x;       // (b, h, l, e), e fastest
    int e = id & 127;
    int l = (id >> 7) & 255;
    int h = (id >> 15) & 1;
    int b = id >> 16;
    const float* pkr = pk + (b * TC + h * 64) * L + l;
    const float* wr = wpq + (h * 64) * TC + e;
    float acc = 0.f;
    #pragma unroll 8
    for (int d = 0; d < 64; d++) acc += pkr[d * L] * wr[d * TC];
    pkqo[id] = f2b(acc * 0.125f);
}

// ---------------- f32 -> bf16 convert (w_fb) ----------------
__global__ void k_cvt_w(const float* __restrict__ w, ushort_t* __restrict__ o, int n) {
    int i = blockIdx.x * 256 + threadIdx.x;
    if (i < n) o[i] = f2b(w[i]);
}

// ---------------- fused MFMA projector ----------------
// 64 points/block, 4 waves; wave w owns points p = w*16..w*16+15 end-to-end.
// MFMA 16x16x32 bf16. A: row=lane&15, k=(lane>>4)*8+j. D: col=lane&15, row=(lane>>4)*4+reg.
// LDS tiles stored [row][k] with 16B-block XOR swizzle blk^=(row&7): write & read use same involution.
__global__ __launch_bounds__(256) void k_proj(const float* __restrict__ f,
                                              const ushort_t* __restrict__ wfb16,   // (128,64) bf16
                                              const ushort_t* __restrict__ pkq16,   // (B,2,256,128) bf16 pre-scaled
                                              const ushort_t* __restrict__ pv16,    // (B,128,256) bf16
                                              float* __restrict__ out, int N) {
    const int b = blockIdx.y;
    const int n0 = blockIdx.x * 64;
    const int tid = threadIdx.x;
    const int w = tid >> 6;
    const int lane = tid & 63;
    const int g = lane >> 4, cc = lane & 15;
    const int p = w * 16 + cc;                      // this lane's point column (local)

    __shared__ __align__(16) ushort_t Pl[4][4096];  // 32KB: per-wave P [16p][256l] swizzled; Pl[0] aliases ft
    __shared__ __align__(16) ushort_t xt[64 * 128]; // 16KB: x [64p][128e] bf16 swizzled
    ushort_t* ft = &Pl[0][0];                       // 8KB f tile [64p][64c] swizzled (dead after phase 1)

    // ---- phase 0: stage f tile, convert f32->bf16, swizzled LDS write ----
    #pragma unroll
    for (int i = 0; i < 16; i++) {
        int lin = tid + i * 256;                    // 64c x 64p
        int c = lin >> 6, pp = lin & 63;
        int n = n0 + pp;
        float v = (n < N) ? f[((size_t)b * CIN + c) * N + n] : 0.f;
        int idx = pp * 64 + ((((c >> 3) ^ (pp & 7)) << 3)) + (c & 7);
        ft[idx] = f2b(v);
    }
    __syncthreads();

    // ---- phase 1: x[128e][64p] = wfb(128x64) @ f(64x64) ----
    f32x4 xacc[8];
    #pragma unroll
    for (int et = 0; et < 8; et++) xacc[et] = (f32x4){0.f, 0.f, 0.f, 0.f};
    #pragma unroll
    for (int kk = 0; kk < 2; kk++) {
        bf16x8 fb = *(const bf16x8*)&ft[p * 64 + (((kk * 4 + g) ^ (cc & 7)) << 3)];
        #pragma unroll
        for (int et = 0; et < 8; et++) {
            bf16x8 a = *(const bf16x8*)&wfb16[(et * 16 + cc) * 64 + kk * 32 + g * 8];
            xacc[et] = __builtin_amdgcn_mfma_f32_16x16x32_bf16(a, fb, xacc[et], 0, 0, 0);
        }
    }
    __syncthreads();    // all ft reads done (ft region becomes wave 0's P buffer)

    // write x to LDS (bf16, swizzled), keep f32 copy in xacc for residual
    #pragma unroll
    for (int et = 0; et < 8; et++) {
        ushort4 q;
        q.x = f2b(xacc[et][0]); q.y = f2b(xacc[et][1]);
        q.z = f2b(xacc[et][2]); q.w = f2b(xacc[et][3]);
        int idx = p * 128 + ((((et * 2 + (g >> 1)) ^ (cc & 7)) << 3)) + (g & 1) * 4;
        *(ushort4*)&xt[idx] = q;
    }

    const size_t bN = (size_t)b * 128;

    for (int h = 0; h < 2; h++) {
        // ---- phase 2: s[256l][16p] = pkq(256x128) @ x(128x16) ----
        const ushort_t* pkqh = pkq16 + ((size_t)(b * 2 + h)) * 256 * 128;
        f32x4 sacc[16];
        #pragma unroll
        for (int lt = 0; lt < 16; lt++) sacc[lt] = (f32x4){0.f, 0.f, 0.f, 0.f};
        bf16x8 xb[4];
        #pragma unroll
        for (int ks = 0; ks < 4; ks++)
            xb[ks] = *(const bf16x8*)&xt[p * 128 + (((ks * 4 + g) ^ (cc & 7)) << 3)];
        #pragma unroll
        for (int lt = 0; lt < 16; lt++) {
            const ushort_t* arow = pkqh + (lt * 16 + cc) * 128 + g * 8;
            #pragma unroll
            for (int ks = 0; ks < 4; ks++) {
                bf16x8 a = *(const bf16x8*)&arow[ks * 32];
                sacc[lt] = __builtin_amdgcn_mfma_f32_16x16x32_bf16(a, xb[ks], sacc[lt], 0, 0, 0);
            }
        }

        // ---- softmax over l (lane holds 64 of 256 values for its point p) ----
        float m = -1e30f;
        #pragma unroll
        for (int lt = 0; lt < 16; lt++) {
            m = fmaxf(m, fmaxf(fmaxf(sacc[lt][0], sacc[lt][1]), fmaxf(sacc[lt][2], sacc[lt][3])));
        }
        m = fmaxf(m, __shfl_xor(m, 16));
        m = fmaxf(m, __shfl_xor(m, 32));
        float z = 0.f;
        #pragma unroll
        for (int lt = 0; lt < 16; lt++) {
            float e0 = __expf(sacc[lt][0] - m), e1 = __expf(sacc[lt][1] - m);
            float e2 = __expf(sacc[lt][2] - m), e3 = __expf(sacc[lt][3] - m);
            z += (e0 + e1) + (e2 + e3);
            ushort4 q;
            q.x = f2b(e0); q.y = f2b(e1); q.z = f2b(e2); q.w = f2b(e3);
            int idx = cc * 256 + ((((lt * 2 + (g >> 1)) ^ (cc & 7)) << 3)) + (g & 1) * 4;
            *(ushort4*)&Pl[w][idx] = q;
        }
        z += __shfl_xor(z, 16);
        z += __shfl_xor(z, 32);

        // ---- phase 3: o[64d][16p] = pv_h(64x256) @ P(256x16) ----
        f32x4 oacc[4];
        #pragma unroll
        for (int dt = 0; dt < 4; dt++) oacc[dt] = (f32x4){0.f, 0.f, 0.f, 0.f};
        const ushort_t* pvh = pv16 + (bN + h * 64) * 256;
        #pragma unroll
        for (int ks2 = 0; ks2 < 8; ks2++) {
            bf16x8 pb = *(const bf16x8*)&Pl[w][cc * 256 + (((ks2 * 4 + g) ^ (cc & 7)) << 3)];
            #pragma unroll
            for (int dt = 0; dt < 4; dt++) {
                bf16x8 a = *(const bf16x8*)&pvh[(dt * 16 + cc) * 256 + ks2 * 32 + g * 8];
                oacc[dt] = __builtin_amdgcn_mfma_f32_16x16x32_bf16(a, pb, oacc[dt], 0, 0, 0);
            }
        }

        // ---- epilogue: out = x + o/Z ----
        float inv = 1.f / z;
        int n = n0 + p;
        if (n < N) {
            #pragma unroll
            for (int dt = 0; dt < 4; dt++) {
                #pragma unroll
                for (int r = 0; r < 4; r++) {
                    int d = h * 64 + dt * 16 + g * 4 + r;
                    out[(bN + d) * N + n] = xacc[h * 4 + dt][r] + oacc[dt][r] * inv;
                }
            }
        }
    }
}

extern "C" void kernel_launch(void* const* d_in, const int* in_sizes, int n_in,
                              void* d_out, int out_size, void* d_ws, size_t ws_size,
                              hipStream_t stream) {
    const float* f        = (const float*)d_in[0];
    const float* in_tok   = (const float*)d_in[1];
    const int*   knn      = (const int*)d_in[2];
    const float* w_dyn1   = (const float*)d_in[3];
    const float* w_dyn2   = (const float*)d_in[4];
    const float* w_fb     = (const float*)d_in[5];
    const float* w_k      = (const float*)d_in[6];
    const float* w_q      = (const float*)d_in[7];
    const float* w_v      = (const float*)d_in[8];
    const float* w_ff1    = (const float*)d_in[9];
    const float* w_ff2    = (const float*)d_in[10];
    const float* w_pv     = (const float*)d_in[11];
    const float* w_pk     = (const float*)d_in[12];
    const float* w_pq     = (const float*)d_in[13];

    float* out   = (float*)d_out;
    float* t_out = out + (size_t)B * 128 * NPT;

    float* ws     = (float*)d_ws;
    float* pooled = ws;                  // 131072
    float* tok1   = pooled + 131072;     // 262144
    float* tokens = tok1 + 262144;       // 262144
    float* kmat   = tokens + 262144;     // 131072
    float* qmat   = kmat + 131072;       // 131072
    float* vmat   = qmat + 131072;       // 262144
    float* attn   = vmat + 262144;       // 1048576
    float* t1     = attn + 1048576;      // 262144
    float* ff1    = t1 + 262144;         // 524288
    float* tfin   = ff1 + 524288;        // 262144
    float* pkb    = tfin + 262144;       // 262144
    ushort_t* pkq16 = (ushort_t*)(pkb + 262144);   // 524288 ushorts
    ushort_t* pv16  = pkq16 + 524288;              // 262144 ushorts
    ushort_t* wfb16 = pv16 + 262144;               // 8192 ushorts

    k_cvt_w<<<32, 256, 0, stream>>>(w_fb, wfb16, 8192);
    k_gather<<<512, 256, 0, stream>>>(f, knn, pooled);
    k_conv<128, 64, true ><<<B * 128, 256, 0, stream>>>(pooled, w_dyn1, nullptr, tok1, nullptr, nullptr);
    k_conv<128, 128, false><<<B * 128, 256, 0, stream>>>(tok1, w_dyn2, in_tok, tokens, nullptr, nullptr);
    k_conv<64, 128, false><<<B * 64, 256, 0, stream>>>(tokens, w_k, nullptr, kmat, nullptr, nullptr);
    k_conv<64, 128, false><<<B * 64, 256, 0, stream>>>(tokens, w_q, nullptr, qmat, nullptr, nullptr);
    k_conv<128, 128, false><<<B * 128, 256, 0, stream>>>(tokens, w_v, nullptr, vmat, nullptr, nullptr);
    k_attn<<<B * 2 * 256, 256, 0, stream>>>(kmat, qmat, attn);
    k_kqv<<<B * 128, 256, 0, stream>>>(vmat, attn, tokens, t1);
    k_conv<256, 128, true ><<<B * 256, 256, 0, stream>>>(t1, w_ff1, nullptr, ff1, nullptr, nullptr);
    k_conv<128, 256, false><<<B * 128, 256, 0, stream>>>(ff1, w_ff2, t1, tfin, t_out, nullptr);
    k_conv<128, 128, false><<<B * 128, 256, 0, stream>>>(tfin, w_pv, nullptr, nullptr, nullptr, pv16);
    k_conv<128, 128, false><<<B * 128, 256, 0, stream>>>(tfin, w_pk, nullptr, pkb, nullptr, nullptr);
    k_pkq<<<2048, 256, 0, stream>>>(pkb, w_pq, pkq16);

    dim3 g((NPT + 63) / 64, B);
    k_proj<<<g, 256, 0, stream>>>(f, wfb16, pkq16, pv16, out, NPT);
}

// Round 7
// 869.240 us; speedup vs baseline: 5.7616x; 1.1883x over previous
//
#include <hip/hip_runtime.h>

#define B 8
#define CIN 64
#define NPT 50000
#define L 256
#define TC 128

typedef unsigned short ushort_t;
typedef __bf16 bf16x8 __attribute__((ext_vector_type(8)));
typedef float f32x4 __attribute__((ext_vector_type(4)));

__device__ __forceinline__ ushort_t f2b(float v) {
    union { float f; unsigned int u; } x; x.f = v;
    unsigned int r = x.u + 0x7FFFu + ((x.u >> 16) & 1u);
    return (ushort_t)(r >> 16);
}

// async global->LDS, 16B per lane; LDS dest = uniform base + lane*16
__device__ __forceinline__ void gl_lds16(const ushort_t* g, ushort_t* l) {
    __builtin_amdgcn_global_load_lds(
        (const __attribute__((address_space(1))) unsigned int*)g,
        (__attribute__((address_space(3))) unsigned int*)l,
        16, 0, 0);
}

// ---------------- KNN gather + max-pool ----------------
__global__ void k_gather(const float* __restrict__ f, const int* __restrict__ knn,
                         float* __restrict__ pooled) {
    int id = blockIdx.x * 256 + threadIdx.x;
    int l = id & 255;
    int c = (id >> 8) & 63;
    int b = id >> 14;
    const int* kn = knn + (b * L + l) * 32;
    const float* fr = f + (b * CIN + c) * NPT;
    float m = -1e30f;
    #pragma unroll 8
    for (int k = 0; k < 32; k++) m = fmaxf(m, fr[kn[k]]);
    pooled[(b * CIN + c) * L + l] = m;
}

// ---------------- generic 1x1 conv over tokens ----------------
template <int O, int C, bool RELU>
__global__ void k_conv(const float* __restrict__ in, const float* __restrict__ w,
                       const float* __restrict__ res, float* __restrict__ out,
                       float* __restrict__ out2, ushort_t* __restrict__ outb) {
    int id = blockIdx.x * 256 + threadIdx.x;
    int l = id & 255;
    int o = (id >> 8) % O;
    int b = id / (O * 256);
    const float* ir = in + b * C * L + l;
    const float* wr = w + o * C;
    float acc = 0.f;
    #pragma unroll 8
    for (int c = 0; c < C; c++) acc += wr[c] * ir[c * L];
    if (RELU) acc = fmaxf(acc, 0.f);
    if (res) acc += res[id];
    if (out)  out[id] = acc;
    if (out2) out2[id] = acc;
    if (outb) outb[id] = f2b(acc);
}

// ---------------- token attention ----------------
__global__ void k_attn(const float* __restrict__ kmat, const float* __restrict__ qmat,
                       float* __restrict__ attn) {
    int blk = blockIdx.x;
    int m = blk & 255;
    int h = (blk >> 8) & 1;
    int b = blk >> 9;
    int n = threadIdx.x;
    const float* kr = kmat + (b * 64 + h * 32) * L + n;
    const float* qr = qmat + (b * 64 + h * 32) * L + m;
    float s = 0.f;
    #pragma unroll
    for (int d = 0; d < 32; d++) s += kr[d * L] * qr[d * L];
    s *= (1.f / 16.f);
    __shared__ float sm[256];
    sm[n] = s;
    __syncthreads();
    for (int st = 128; st > 0; st >>= 1) { if (n < st) sm[n] = fmaxf(sm[n], sm[n + st]); __syncthreads(); }
    float mx = sm[0];
    __syncthreads();
    float p = __expf(s - mx);
    sm[n] = p;
    __syncthreads();
    for (int st = 128; st > 0; st >>= 1) { if (n < st) sm[n] += sm[n + st]; __syncthreads(); }
    float Z = sm[0];
    attn[((b * 2 + h) * L + n) * L + m] = p / Z;
}

// ---------------- kqv + residual ----------------
__global__ void k_kqv(const float* __restrict__ vmat, const float* __restrict__ attn,
                      const float* __restrict__ tokens, float* __restrict__ t1) {
    int id = blockIdx.x * 256 + threadIdx.x;
    int m = id & 255;
    int ch = (id >> 8) & 127;
    int b = id >> 15;
    int h = ch >> 6;
    const float* vr = vmat + (b * TC + ch) * L;
    const float* ar = attn + ((b * 2 + h) * L) * L + m;
    float acc = 0.f;
    #pragma unroll 8
    for (int n = 0; n < L; n++) acc += vr[n] * ar[n * L];
    t1[id] = tokens[id] + acc;
}

// ---------------- pkq (bf16 out, pre-scaled by 1/8) ----------------
__global__ void k_pkq(const float* __restrict__ pk, const float* __restrict__ wpq,
                      ushort_t* __restrict__ pkqo) {
    int id = blockIdx.x * 256 + threadIdx.x;       // (b, h, l, e), e fastest
    int e = id & 127;
    int l = (id >> 7) & 255;
    int h = (id >> 15) & 1;
    int b = id >> 16;
    const float* pkr = pk + (b * TC + h * 64) * L + l;
    const float* wr = wpq + (h * 64) * TC + e;
    float acc = 0.f;
    #pragma unroll 8
    for (int d = 0; d < 64; d++) acc += pkr[d * L] * wr[d * TC];
    pkqo[id] = f2b(acc * 0.125f);
}

// ---------------- f32 -> bf16 convert (w_fb) ----------------
__global__ void k_cvt_w(const float* __restrict__ w, ushort_t* __restrict__ o, int n) {
    int i = blockIdx.x * 256 + threadIdx.x;
    if (i < n) o[i] = f2b(w[i]);
}

// ---------------- fused MFMA projector v2: chunk-staged A operands ----------------
// 64 points/block, 4 waves; wave w owns points p = w*16..w*16+15.
// pkq/pv staged block-cooperatively in 64-row chunks (16KB / 8KB), double-buffered,
// stage(j+1) issued before compute(j); one __syncthreads per job (vmcnt drain = our wait).
// All LDS tiles 16B-block XOR-swizzled (blk ^= row&7) on BOTH sides (staging source
// pre-swizzled, linear LDS dest) -> conflict-free ds_read_b128 fragments.
__global__ __launch_bounds__(256) void k_proj(const float* __restrict__ f,
                                              const ushort_t* __restrict__ wfb16,   // (128,64)
                                              const ushort_t* __restrict__ pkq16,   // (B,2,256,128) pre-scaled
                                              const ushort_t* __restrict__ pv16,    // (B,128,256)
                                              float* __restrict__ out, int N) {
    const int b = blockIdx.y;
    const int n0 = blockIdx.x * 64;
    const int tid = threadIdx.x;
    const int w = tid >> 6;
    const int lane = tid & 63;
    const int g = lane >> 4, cc = lane & 15;
    const int p = w * 16 + cc;

    __shared__ __align__(16) ushort_t Pl[4][4096];   // 32KB per-wave P [16p][256l] swz
    __shared__ __align__(16) ushort_t xt[64 * 128];  // 16KB x [64p][128e] swz
    __shared__ __align__(16) ushort_t stg[2][8192];  // 32KB double-buffered A chunks
    ushort_t* ft = &Pl[0][0];                        // 8KB f tile alias (dead after phase 1)

    const size_t bN = (size_t)b * 128;
    const ushort_t* pkqb = pkq16 + (size_t)(b * 2) * 256 * 128;
    const ushort_t* pvb  = pv16 + bN * 256;

    // ---- stage helpers: linear LDS dest, inverse-swizzled global source ----
    auto STAGE_PKQ = [&](int h, int ch, int buf) {   // 64 l-rows x 128 e = 16KB
        const ushort_t* src = pkqb + (size_t)h * 256 * 128 + ch * 64 * 128;
        #pragma unroll
        for (int i = 0; i < 4; i++) {
            int bo = (w * 4 + i) * 64 + lane;        // 16B-block index 0..1023
            int row = bo >> 4, cb = bo & 15;
            gl_lds16(src + row * 128 + ((cb ^ (row & 7)) << 3),
                     &stg[buf][(w * 4 + i) * 512]);
        }
    };
    auto STAGE_PV = [&](int h, int ch, int buf) {    // 64 d-rows x 64 l = 8KB
        const ushort_t* src = pvb + (size_t)h * 64 * 256 + ch * 64;
        #pragma unroll
        for (int i = 0; i < 2; i++) {
            int bo = (w * 2 + i) * 64 + lane;        // 16B-block index 0..511
            int row = bo >> 3, cb = bo & 7;
            gl_lds16(src + row * 256 + ((cb ^ (row & 7)) << 3),
                     &stg[buf][(w * 2 + i) * 512]);
        }
    };

    // ---- prologue: issue first pkq chunk, stage f tile ----
    STAGE_PKQ(0, 0, 0);
    #pragma unroll
    for (int i = 0; i < 16; i++) {
        int lin = tid + i * 256;                     // 64c x 64p
        int c = lin >> 6, pp = lin & 63;
        int n = n0 + pp;
        float v = (n < N) ? f[((size_t)b * CIN + c) * N + n] : 0.f;
        int idx = pp * 64 + ((((c >> 3) ^ (pp & 7)) << 3)) + (c & 7);
        ft[idx] = f2b(v);
    }
    __syncthreads();                                 // f tile ready; stg[0] drained

    // ---- phase 1: x[128e][64p] = wfb(128x64) @ f(64x64) ----
    f32x4 xacc[8];
    #pragma unroll
    for (int et = 0; et < 8; et++) xacc[et] = (f32x4){0.f, 0.f, 0.f, 0.f};
    #pragma unroll
    for (int kk = 0; kk < 2; kk++) {
        bf16x8 fb = *(const bf16x8*)&ft[p * 64 + (((kk * 4 + g) ^ (cc & 7)) << 3)];
        #pragma unroll
        for (int et = 0; et < 8; et++) {
            bf16x8 a = *(const bf16x8*)&wfb16[(et * 16 + cc) * 64 + kk * 32 + g * 8];
            xacc[et] = __builtin_amdgcn_mfma_f32_16x16x32_bf16(a, fb, xacc[et], 0, 0, 0);
        }
    }
    // write x to LDS bf16 (own wave's rows; wave-local consistency, no barrier needed)
    #pragma unroll
    for (int et = 0; et < 8; et++) {
        ushort4 q;
        q.x = f2b(xacc[et][0]); q.y = f2b(xacc[et][1]);
        q.z = f2b(xacc[et][2]); q.w = f2b(xacc[et][3]);
        int idx = p * 128 + ((((et * 2 + (g >> 1)) ^ (cc & 7)) << 3)) + (g & 1) * 4;
        *(ushort4*)&xt[idx] = q;
    }
    // B-frags of x for phase 2 (same for both heads)
    bf16x8 xb[4];
    #pragma unroll
    for (int ks = 0; ks < 4; ks++)
        xb[ks] = *(const bf16x8*)&xt[p * 128 + (((ks * 4 + g) ^ (cc & 7)) << 3)];

    int buf = 0;
    #pragma unroll
    for (int h = 0; h < 2; h++) {
        // ---- phase 2: s[256l][16p] = pkq_h @ x, 4 staged chunks ----
        f32x4 sacc[16];
        #pragma unroll
        for (int lt = 0; lt < 16; lt++) sacc[lt] = (f32x4){0.f, 0.f, 0.f, 0.f};
        #pragma unroll
        for (int ch = 0; ch < 4; ch++) {
            if (ch < 3) STAGE_PKQ(h, ch + 1, buf ^ 1);
            else        STAGE_PV(h, 0, buf ^ 1);
            #pragma unroll
            for (int lt = 0; lt < 4; lt++) {
                const int row = lt * 16 + cc;
                #pragma unroll
                for (int ks = 0; ks < 4; ks++) {
                    bf16x8 a = *(const bf16x8*)&stg[buf][row * 128 + (((ks * 4 + g) ^ (cc & 7)) << 3)];
                    sacc[ch * 4 + lt] = __builtin_amdgcn_mfma_f32_16x16x32_bf16(a, xb[ks], sacc[ch * 4 + lt], 0, 0, 0);
                }
            }
            __syncthreads();
            buf ^= 1;
        }

        // ---- softmax over l (per-wave; lane holds 64 of 256 scores for point p) ----
        float m = -1e30f;
        #pragma unroll
        for (int lt = 0; lt < 16; lt++)
            m = fmaxf(m, fmaxf(fmaxf(sacc[lt][0], sacc[lt][1]), fmaxf(sacc[lt][2], sacc[lt][3])));
        m = fmaxf(m, __shfl_xor(m, 16));
        m = fmaxf(m, __shfl_xor(m, 32));
        float z = 0.f;
        #pragma unroll
        for (int lt = 0; lt < 16; lt++) {
            float e0 = __expf(sacc[lt][0] - m), e1 = __expf(sacc[lt][1] - m);
            float e2 = __expf(sacc[lt][2] - m), e3 = __expf(sacc[lt][3] - m);
            z += (e0 + e1) + (e2 + e3);
            ushort4 q;
            q.x = f2b(e0); q.y = f2b(e1); q.z = f2b(e2); q.w = f2b(e3);
            int idx = cc * 256 + ((((lt * 2 + (g >> 1)) ^ (cc & 7)) << 3)) + (g & 1) * 4;
            *(ushort4*)&Pl[w][idx] = q;
        }
        z += __shfl_xor(z, 16);
        z += __shfl_xor(z, 32);

        // ---- phase 3: o[64d][16p] = pv_h @ P, 4 staged chunks over l ----
        f32x4 oacc[4];
        #pragma unroll
        for (int dt = 0; dt < 4; dt++) oacc[dt] = (f32x4){0.f, 0.f, 0.f, 0.f};
        #pragma unroll
        for (int ch = 0; ch < 4; ch++) {
            if (ch < 3)      STAGE_PV(h, ch + 1, buf ^ 1);
            else if (h == 0) STAGE_PKQ(1, 0, buf ^ 1);
            #pragma unroll
            for (int dt = 0; dt < 4; dt++) {
                const int row = dt * 16 + cc;
                #pragma unroll
                for (int ks2 = 0; ks2 < 2; ks2++) {
                    bf16x8 a = *(const bf16x8*)&stg[buf][row * 64 + (((ks2 * 4 + g) ^ (cc & 7)) << 3)];
                    bf16x8 pb = *(const bf16x8*)&Pl[w][cc * 256 + ((((ch * 2 + ks2) * 4 + g) ^ (cc & 7)) << 3)];
                    oacc[dt] = __builtin_amdgcn_mfma_f32_16x16x32_bf16(a, pb, oacc[dt], 0, 0, 0);
                }
            }
            __syncthreads();
            buf ^= 1;
        }

        // ---- epilogue: out = x + o/Z ----
        float inv = 1.f / z;
        int n = n0 + p;
        if (n < N) {
            #pragma unroll
            for (int dt = 0; dt < 4; dt++) {
                #pragma unroll
                for (int r = 0; r < 4; r++) {
                    int d = h * 64 + dt * 16 + g * 4 + r;
                    out[(bN + d) * N + n] = xacc[h * 4 + dt][r] + oacc[dt][r] * inv;
                }
            }
        }
    }
}

extern "C" void kernel_launch(void* const* d_in, const int* in_sizes, int n_in,
                              void* d_out, int out_size, void* d_ws, size_t ws_size,
                              hipStream_t stream) {
    const float* f        = (const float*)d_in[0];
    const float* in_tok   = (const float*)d_in[1];
    const int*   knn      = (const int*)d_in[2];
    const float* w_dyn1   = (const float*)d_in[3];
    const float* w_dyn2   = (const float*)d_in[4];
    const float* w_fb     = (const float*)d_in[5];
    const float* w_k      = (const float*)d_in[6];
    const float* w_q      = (const float*)d_in[7];
    const float* w_v      = (const float*)d_in[8];
    const float* w_ff1    = (const float*)d_in[9];
    const float* w_ff2    = (const float*)d_in[10];
    const float* w_pv     = (const float*)d_in[11];
    const float* w_pk     = (const float*)d_in[12];
    const float* w_pq     = (const float*)d_in[13];

    float* out   = (float*)d_out;
    float* t_out = out + (size_t)B * 128 * NPT;

    float* ws     = (float*)d_ws;
    float* pooled = ws;                  // 131072
    float* tok1   = pooled + 131072;     // 262144
    float* tokens = tok1 + 262144;       // 262144
    float* kmat   = tokens + 262144;     // 131072
    float* qmat   = kmat + 131072;       // 131072
    float* vmat   = qmat + 131072;       // 262144
    float* attn   = vmat + 262144;       // 1048576
    float* t1     = attn + 1048576;      // 262144
    float* ff1    = t1 + 262144;         // 524288
    float* tfin   = ff1 + 524288;        // 262144
    float* pkb    = tfin + 262144;       // 262144
    ushort_t* pkq16 = (ushort_t*)(pkb + 262144);   // 524288 ushorts
    ushort_t* pv16  = pkq16 + 524288;              // 262144 ushorts
    ushort_t* wfb16 = pv16 + 262144;               // 8192 ushorts

    k_cvt_w<<<32, 256, 0, stream>>>(w_fb, wfb16, 8192);
    k_gather<<<512, 256, 0, stream>>>(f, knn, pooled);
    k_conv<128, 64, true ><<<B * 128, 256, 0, stream>>>(pooled, w_dyn1, nullptr, tok1, nullptr, nullptr);
    k_conv<128, 128, false><<<B * 128, 256, 0, stream>>>(tok1, w_dyn2, in_tok, tokens, nullptr, nullptr);
    k_conv<64, 128, false><<<B * 64, 256, 0, stream>>>(tokens, w_k, nullptr, kmat, nullptr, nullptr);
    k_conv<64, 128, false><<<B * 64, 256, 0, stream>>>(tokens, w_q, nullptr, qmat, nullptr, nullptr);
    k_conv<128, 128, false><<<B * 128, 256, 0, stream>>>(tokens, w_v, nullptr, vmat, nullptr, nullptr);
    k_attn<<<B * 2 * 256, 256, 0, stream>>>(kmat, qmat, attn);
    k_kqv<<<B * 128, 256, 0, stream>>>(vmat, attn, tokens, t1);
    k_conv<256, 128, true ><<<B * 256, 256, 0, stream>>>(t1, w_ff1, nullptr, ff1, nullptr, nullptr);
    k_conv<128, 256, false><<<B * 128, 256, 0, stream>>>(ff1, w_ff2, t1, tfin, t_out, nullptr);
    k_conv<128, 128, false><<<B * 128, 256, 0, stream>>>(tfin, w_pv, nullptr, nullptr, nullptr, pv16);
    k_conv<128, 128, false><<<B * 128, 256, 0, stream>>>(tfin, w_pk, nullptr, pkb, nullptr, nullptr);
    k_pkq<<<2048, 256, 0, stream>>>(pkb, w_pq, pkq16);

    dim3 g((NPT + 63) / 64, B);
    k_proj<<<g, 256, 0, stream>>>(f, wfb16, pkq16, pv16, out, NPT);
}